// Round 6
// baseline (940.120 us; speedup 1.0000x reference)
//
#include <hip/hip_runtime.h>
#include <hip/hip_bf16.h>
#include <hip/hip_cooperative_groups.h>

// GRNN tree transform v4.1: ONE cooperative kernel (wcast + leaf + 12 levels,
// grid.sync between levels). Persistent blocks, 64-node tiles, single staging
// phase per tile (8 gather loads in flight covered by fused-u VALU), 3x8 MFMA.
// v4 bug fixed: gather-landing offset ph*256 -> ph*128 (elements, not bytes);
// hR now lands in cols 128..255 instead of clobbering u (cols 256..383).
// Fallback to the round-4 multi-launch path if cooperative launch is refused.

#define NF 7
#define NH 128
#define NLEAF 262144
#define XSTR 136      // round-4 k_inner stride (fallback path)
#define XSTR3 392     // 384 + 8 pad; row = 784 B (16B-aligned)

namespace cg = cooperative_groups;

typedef __bf16 bf16;
typedef __bf16 bf16x8 __attribute__((ext_vector_type(8)));
typedef float floatx16 __attribute__((ext_vector_type(16)));

__device__ __forceinline__ float ftanh(float x){
    float e = __expf(2.0f * x);
    return 1.0f - __fdividef(2.0f, e + 1.0f);
}

// ======================= cooperative all-in-one kernel =======================
__global__ __launch_bounds__(256, 3) void k_all(
    const float* __restrict__ contents, const int2* __restrict__ children,
    const float* __restrict__ w_u, const float* __restrict__ b_u,
    const float* __restrict__ w_h, const float* __restrict__ b_h,
    bf16* __restrict__ embA, bf16* __restrict__ embB,
    bf16* __restrict__ wb, float* __restrict__ out_f)
{
    cg::grid_group grid = cg::this_grid();
    __shared__ bf16 xs[64 * XSTR3];   // 50176 B (also reused as float cs for leaf)
    __shared__ int2 ch_s[64];         // 512 B
    __shared__ float cs[64 * 8];      // 2048 B  -> 52736 B total, 3 blocks/CU

    const int t = threadIdx.x;
    const int cp = t & 63;            // col-pair for u phases
    const int quarter = t >> 6;
    const int lane = t & 63;
    const int ct = t >> 6;            // col-tile (wave id)
    const int m = lane & 31;
    const int q = lane >> 5;

    // --- stage 0: w_h -> bf16 (49152 elements) ---
    {
        int gtid = blockIdx.x * 256 + t;
        if (gtid < NH * 384) wb[gtid] = (bf16)w_h[gtid];
    }

    // persistent per-thread registers
    float wu0[NF], wu1[NF];
    {
        const float* w0 = w_u + (size_t)(2 * cp) * NF;
        #pragma unroll
        for (int f = 0; f < NF; ++f){ wu0[f] = w0[f]; wu1[f] = w0[NF + f]; }
    }
    const float bu0 = b_u[2 * cp], bu1 = b_u[2 * cp + 1];
    const float bv  = b_h[ct * 32 + m];

    grid.sync();   // wb ready

    // --- stage 1: leaf (level 12): 2048 tiles of 128 nodes ---
    {
        const float* contL = contents + (size_t)262080 * NF;
        unsigned int* eA32 = (unsigned int*)embA;
        float* csL = (float*)xs;      // 128*8 floats = 4096 B, fits in xs
        for (int tile = blockIdx.x; tile < 2048; tile += gridDim.x){
            __syncthreads();          // guard csL reuse
            if (t < 224){             // 128*7 floats = 224 float4
                float4 v = ((const float4*)(contL + (size_t)tile * 128 * NF))[t];
                int e = t * 4;
                float vv[4] = {v.x, v.y, v.z, v.w};
                #pragma unroll
                for (int r = 0; r < 4; ++r){
                    int ee = e + r;
                    csL[(ee / 7) * 8 + (ee % 7)] = vv[r];
                }
            }
            __syncthreads();
            #pragma unroll 4
            for (int i = 0; i < 32; ++i){
                int node = quarter * 32 + i;
                float4 c0 = *(const float4*)&csL[node * 8];
                float4 c1 = *(const float4*)&csL[node * 8 + 4];
                float a0 = bu0, a1 = bu1;
                a0 = fmaf(c0.x, wu0[0], a0); a1 = fmaf(c0.x, wu1[0], a1);
                a0 = fmaf(c0.y, wu0[1], a0); a1 = fmaf(c0.y, wu1[1], a1);
                a0 = fmaf(c0.z, wu0[2], a0); a1 = fmaf(c0.z, wu1[2], a1);
                a0 = fmaf(c0.w, wu0[3], a0); a1 = fmaf(c0.w, wu1[3], a1);
                a0 = fmaf(c1.x, wu0[4], a0); a1 = fmaf(c1.x, wu1[4], a1);
                a0 = fmaf(c1.y, wu0[5], a0); a1 = fmaf(c1.y, wu1[5], a1);
                a0 = fmaf(c1.z, wu0[6], a0); a1 = fmaf(c1.z, wu1[6], a1);
                union { unsigned int u; bf16 h[2]; } pk;
                pk.h[0] = (bf16)ftanh(a0);
                pk.h[1] = (bf16)ftanh(a1);
                eA32[(size_t)(tile * 128 + node) * 64 + cp] = pk.u;
            }
        }
    }
    grid.sync();   // embA (leaf emb) ready

    const bf16* bq = wb + ((size_t)(ct * 32 + m) * 384 + q * 8);
    unsigned int* xs32 = (unsigned int*)xs;

    // --- stage 2: levels j=11..0 ---
    for (int j = 11; j >= 0; --j){
        const int ntiles = 1 << j;            // M/64
        const size_t lvl = (size_t)64 * ((1u << j) - 1);
        const int2* ch = children + lvl;
        const float* cont = contents + lvl * NF;
        const bf16* eN = ((j + 1) & 1) ? embB : embA;
        bf16* oB = (j & 1) ? embB : embA;

        for (int tile = blockIdx.x; tile < ntiles; tile += gridDim.x){
            const int block0 = tile * 64;
            __syncthreads();                  // guard LDS reuse from prev tile
            if (t < 64) ch_s[t] = ch[block0 + t];
            if (t < 112){                     // 64*7 floats = 112 float4
                float4 v = ((const float4*)(cont + (size_t)block0 * NF))[t];
                int e = t * 4;
                float vv[4] = {v.x, v.y, v.z, v.w};
                #pragma unroll
                for (int r = 0; r < 4; ++r){
                    int ee = e + r;
                    cs[(ee / 7) * 8 + (ee % 7)] = vv[r];
                }
            }
            __syncthreads();                  // ch_s / cs ready

            // issue all 8 gather loads (hL: tasks 0..1023, hR: 1024..2047)
            uint4 g[8];
            #pragma unroll
            for (int r = 0; r < 8; ++r){
                int task = r * 256 + t;
                int i = (task >> 4) & 63;
                int part = task & 15;
                int2 c2 = ch_s[i];
                int row = (task < 1024) ? c2.x : c2.y;
                g[r] = *(const uint4*)(eN + (size_t)row * NH + part * 8);
            }

            // fused u (independent VALU covers gather latency): cols 256..383
            #pragma unroll 4
            for (int i = 0; i < 16; ++i){
                int node = quarter * 16 + i;
                float4 c0 = *(const float4*)&cs[node * 8];
                float4 c1 = *(const float4*)&cs[node * 8 + 4];
                float a0 = bu0, a1 = bu1;
                a0 = fmaf(c0.x, wu0[0], a0); a1 = fmaf(c0.x, wu1[0], a1);
                a0 = fmaf(c0.y, wu0[1], a0); a1 = fmaf(c0.y, wu1[1], a1);
                a0 = fmaf(c0.z, wu0[2], a0); a1 = fmaf(c0.z, wu1[2], a1);
                a0 = fmaf(c0.w, wu0[3], a0); a1 = fmaf(c0.w, wu1[3], a1);
                a0 = fmaf(c1.x, wu0[4], a0); a1 = fmaf(c1.x, wu1[4], a1);
                a0 = fmaf(c1.y, wu0[5], a0); a1 = fmaf(c1.y, wu1[5], a1);
                a0 = fmaf(c1.z, wu0[6], a0); a1 = fmaf(c1.z, wu1[6], a1);
                union { unsigned int u; bf16 h[2]; } pk;
                pk.h[0] = (bf16)ftanh(a0);
                pk.h[1] = (bf16)ftanh(a1);
                xs32[node * (XSTR3 / 2) + 128 + cp] = pk.u;
            }

            // land the gathers in LDS: hL -> cols 0..127, hR -> cols 128..255
            #pragma unroll
            for (int r = 0; r < 8; ++r){
                int task = r * 256 + t;
                int i = (task >> 4) & 63;
                int part = task & 15;
                int ph = task >> 10;          // 0 = hL, 1 = hR
                *(uint4*)&xs[i * XSTR3 + ph * 128 + part * 8] = g[r];
            }
            __syncthreads();                  // xs fully staged

            floatx16 acc0 = {0,0,0,0,0,0,0,0,0,0,0,0,0,0,0,0};
            floatx16 acc1 = {0,0,0,0,0,0,0,0,0,0,0,0,0,0,0,0};
            const bf16* xa = &xs[m * XSTR3 + q * 8];
            #pragma unroll
            for (int grp = 0; grp < 3; ++grp){
                bf16x8 bfr[8];
                #pragma unroll
                for (int kk = 0; kk < 8; ++kk)
                    bfr[kk] = *(const bf16x8*)(bq + grp * 128 + kk * 16);
                #pragma unroll
                for (int kk = 0; kk < 8; ++kk){
                    bf16x8 a0 = *(const bf16x8*)(xa + grp * 128 + kk * 16);
                    bf16x8 a1 = *(const bf16x8*)(xa + grp * 128 + kk * 16 + 32 * XSTR3);
                    acc0 = __builtin_amdgcn_mfma_f32_32x32x16_bf16(a0, bfr[kk], acc0, 0, 0, 0);
                    acc1 = __builtin_amdgcn_mfma_f32_32x32x16_bf16(a1, bfr[kk], acc1, 0, 0, 0);
                }
            }

            // epilogue: C/D col = lane&31, row = (r&3)+8*(r>>2)+4*q
            const int colg = ct * 32 + m;
            #pragma unroll
            for (int nt = 0; nt < 2; ++nt){
                const floatx16* accp = nt ? &acc1 : &acc0;
                #pragma unroll
                for (int r = 0; r < 16; ++r){
                    int row  = (r & 3) + 8 * (r >> 2) + 4 * q;
                    int node = block0 + nt * 32 + row;
                    float v = ftanh((*accp)[r] + bv);
                    if (j == 0) out_f[(size_t)node * NH + colg] = v;
                    else        oB[(size_t)node * NH + colg] = (bf16)v;
                }
            }
        }
        if (j) grid.sync();
    }
}

// ======================= round-4 fallback kernels =======================
__global__ __launch_bounds__(256) void k_wcast(const float* __restrict__ w,
                                               bf16* __restrict__ wb){
    int i = blockIdx.x * 256 + threadIdx.x;
    wb[i] = (bf16)w[i];
}

__global__ __launch_bounds__(256) void k_leaf(const float* __restrict__ contents_leaf,
        const float* __restrict__ w_u, const float* __restrict__ b_u,
        unsigned int* __restrict__ embA_u32){
    __shared__ float csL[128 * 8];
    const int t = threadIdx.x;
    const int block0 = blockIdx.x * 128;
    if (t < 224){
        float4 v = ((const float4*)(contents_leaf + (size_t)block0 * NF))[t];
        int e = t * 4;
        float vv[4] = {v.x, v.y, v.z, v.w};
        #pragma unroll
        for (int r = 0; r < 4; ++r){ int ee = e + r; csL[(ee/7)*8 + (ee%7)] = vv[r]; }
    }
    const int cp = t & 63;
    const int quarter = t >> 6;
    float wu0[NF], wu1[NF];
    const float* w0 = w_u + (size_t)(2 * cp) * NF;
    #pragma unroll
    for (int f = 0; f < NF; ++f){ wu0[f] = w0[f]; wu1[f] = w0[NF + f]; }
    const float bu0 = b_u[2 * cp], bu1 = b_u[2 * cp + 1];
    __syncthreads();
    #pragma unroll 4
    for (int i = 0; i < 32; ++i){
        int node = quarter * 32 + i;
        float4 c0 = *(const float4*)&csL[node * 8];
        float4 c1 = *(const float4*)&csL[node * 8 + 4];
        float a0 = bu0, a1 = bu1;
        a0 = fmaf(c0.x, wu0[0], a0); a1 = fmaf(c0.x, wu1[0], a1);
        a0 = fmaf(c0.y, wu0[1], a0); a1 = fmaf(c0.y, wu1[1], a1);
        a0 = fmaf(c0.z, wu0[2], a0); a1 = fmaf(c0.z, wu1[2], a1);
        a0 = fmaf(c0.w, wu0[3], a0); a1 = fmaf(c0.w, wu1[3], a1);
        a0 = fmaf(c1.x, wu0[4], a0); a1 = fmaf(c1.x, wu1[4], a1);
        a0 = fmaf(c1.y, wu0[5], a0); a1 = fmaf(c1.y, wu1[5], a1);
        a0 = fmaf(c1.z, wu0[6], a0); a1 = fmaf(c1.z, wu1[6], a1);
        union { unsigned int u; bf16 h[2]; } pk;
        pk.h[0] = (bf16)ftanh(a0);
        pk.h[1] = (bf16)ftanh(a1);
        embA_u32[(size_t)(block0 + node) * 64 + cp] = pk.u;
    }
}

__global__ __launch_bounds__(256, 4) void k_inner(
    const int2* __restrict__ children, const float* __restrict__ contents,
    const float* __restrict__ w_u, const float* __restrict__ b_u,
    const bf16* __restrict__ wb, const float* __restrict__ b_h,
    const bf16* __restrict__ emb_next, bf16* __restrict__ out_b,
    float* __restrict__ out_f, int f32out)
{
    __shared__ bf16 xs[64 * XSTR];
    __shared__ int2 ch_s[64];
    __shared__ float cs[64 * 8];
    const int t = threadIdx.x;
    const int block0 = blockIdx.x * 64;
    if (t < 64) ch_s[t] = children[block0 + t];
    if (t < 112){
        float4 v = ((const float4*)(contents + (size_t)block0 * NF))[t];
        int e = t * 4;
        float vv[4] = {v.x, v.y, v.z, v.w};
        #pragma unroll
        for (int r = 0; r < 4; ++r){ int ee = e + r; cs[(ee/7)*8 + (ee%7)] = vv[r]; }
    }
    const int cp = t & 63;
    const int quarter = t >> 6;
    float wu0[NF], wu1[NF];
    {
        const float* w0 = w_u + (size_t)(2 * cp) * NF;
        #pragma unroll
        for (int f = 0; f < NF; ++f){ wu0[f] = w0[f]; wu1[f] = w0[NF + f]; }
    }
    const float bu0 = b_u[2 * cp], bu1 = b_u[2 * cp + 1];
    const int lane = t & 63;
    const int ct = t >> 6;
    const int m = lane & 31;
    const int q = lane >> 5;
    floatx16 acc0 = {0,0,0,0,0,0,0,0,0,0,0,0,0,0,0,0};
    floatx16 acc1 = {0,0,0,0,0,0,0,0,0,0,0,0,0,0,0,0};
    const bf16* bq = wb + ((size_t)(ct * 32 + m) * 384 + q * 8);
    #pragma unroll 1
    for (int p = 0; p < 3; ++p){
        __syncthreads();
        if (p < 2){
            #pragma unroll
            for (int r = 0; r < 4; ++r){
                int task = r * 256 + t;
                int i = task >> 4, part = task & 15;
                int row = (p == 0) ? ch_s[i].x : ch_s[i].y;
                uint4 v = *(const uint4*)(emb_next + (size_t)row * NH + part * 8);
                *(uint4*)&xs[i * XSTR + part * 8] = v;
            }
        } else {
            #pragma unroll 4
            for (int i = 0; i < 16; ++i){
                int node = quarter * 16 + i;
                float4 c0 = *(const float4*)&cs[node * 8];
                float4 c1 = *(const float4*)&cs[node * 8 + 4];
                float a0 = bu0, a1 = bu1;
                a0 = fmaf(c0.x, wu0[0], a0); a1 = fmaf(c0.x, wu1[0], a1);
                a0 = fmaf(c0.y, wu0[1], a0); a1 = fmaf(c0.y, wu1[1], a1);
                a0 = fmaf(c0.z, wu0[2], a0); a1 = fmaf(c0.z, wu1[2], a1);
                a0 = fmaf(c0.w, wu0[3], a0); a1 = fmaf(c0.w, wu1[3], a1);
                a0 = fmaf(c1.x, wu0[4], a0); a1 = fmaf(c1.x, wu1[4], a1);
                a0 = fmaf(c1.y, wu0[5], a0); a1 = fmaf(c1.y, wu1[5], a1);
                a0 = fmaf(c1.z, wu0[6], a0); a1 = fmaf(c1.z, wu1[6], a1);
                union { unsigned int u; bf16 h[2]; } pk;
                pk.h[0] = (bf16)ftanh(a0);
                pk.h[1] = (bf16)ftanh(a1);
                ((unsigned int*)xs)[node * (XSTR / 2) + cp] = pk.u;
            }
        }
        bf16x8 bfr[8];
        #pragma unroll
        for (int kk = 0; kk < 8; ++kk)
            bfr[kk] = *(const bf16x8*)(bq + p * 128 + kk * 16);
        __syncthreads();
        const bf16* xa = &xs[m * XSTR + q * 8];
        #pragma unroll
        for (int kk = 0; kk < 8; ++kk){
            bf16x8 a0 = *(const bf16x8*)(xa + kk * 16);
            bf16x8 a1 = *(const bf16x8*)(xa + kk * 16 + 32 * XSTR);
            acc0 = __builtin_amdgcn_mfma_f32_32x32x16_bf16(a0, bfr[kk], acc0, 0, 0, 0);
            acc1 = __builtin_amdgcn_mfma_f32_32x32x16_bf16(a1, bfr[kk], acc1, 0, 0, 0);
        }
    }
    const int colg = ct * 32 + m;
    const float bv = b_h[colg];
    #pragma unroll
    for (int nt = 0; nt < 2; ++nt){
        const floatx16* accp = nt ? &acc1 : &acc0;
        #pragma unroll
        for (int r = 0; r < 16; ++r){
            int row  = (r & 3) + 8 * (r >> 2) + 4 * q;
            int node = block0 + nt * 32 + row;
            float v = ftanh((*accp)[r] + bv);
            if (f32out) out_f[(size_t)node * NH + colg] = v;
            else        out_b[(size_t)node * NH + colg] = (bf16)v;
        }
    }
}

// ======================= launcher =======================
extern "C" void kernel_launch(void* const* d_in, const int* in_sizes, int n_in,
                              void* d_out, int out_size, void* d_ws, size_t ws_size,
                              hipStream_t stream){
    const float* contents = (const float*)d_in[0];
    const int2*  children = (const int2*)d_in[1];
    const float* w_u      = (const float*)d_in[2];
    const float* b_u      = (const float*)d_in[3];
    const float* w_h      = (const float*)d_in[4];
    const float* b_h      = (const float*)d_in[5];
    float* outf = (float*)d_out;

    bf16* embA = (bf16*)d_ws;
    bf16* embB = embA + (size_t)NLEAF * NH;
    bf16* wb   = embB + (size_t)131072 * NH;

    // try the cooperative single-kernel path
    int dev = 0; (void)hipGetDevice(&dev);
    int coop = 0;
    (void)hipDeviceGetAttribute(&coop, hipDeviceAttributeCooperativeLaunch, dev);
    int ncu = 0;
    (void)hipDeviceGetAttribute(&ncu, hipDeviceAttributeMultiprocessorCount, dev);
    int occ = 0;
    hipError_t eo = hipOccupancyMaxActiveBlocksPerMultiprocessor(&occ, (const void*)k_all, 256, 0);
    if (coop && eo == hipSuccess && occ >= 1 && ncu >= 1){
        int gridn = occ * ncu;
        if (gridn > 768) gridn = 768;
        void* args[10] = {(void*)&contents, (void*)&children, (void*)&w_u, (void*)&b_u,
                          (void*)&w_h, (void*)&b_h, (void*)&embA, (void*)&embB,
                          (void*)&wb, (void*)&outf};
        hipError_t el = hipLaunchCooperativeKernel((const void*)k_all, dim3(gridn),
                                                   dim3(256), args, 0, stream);
        if (el == hipSuccess) return;
    }

    // fallback: round-4 multi-launch path
    hipLaunchKernelGGL(k_wcast, dim3(192), dim3(256), 0, stream, w_h, wb);
    hipLaunchKernelGGL(k_leaf, dim3(NLEAF / 128), dim3(256), 0, stream,
                       contents + (size_t)262080 * NF, w_u, b_u, (unsigned int*)embA);
    for (int j = 11; j >= 0; --j){
        int M = 64 << j;
        size_t lvl = (size_t)64 * ((1u << j) - 1);
        const bf16* embN = ((j + 1) & 1) ? embB : embA;
        bf16* ob = (j & 1) ? embB : embA;
        hipLaunchKernelGGL(k_inner, dim3(M / 64), dim3(256), 0, stream,
                           children + lvl, contents + lvl * NF, w_u, b_u, wb, b_h, embN,
                           (j == 0) ? (bf16*)nullptr : ob,
                           (j == 0) ? outf : (float*)nullptr,
                           (j == 0) ? 1 : 0);
    }
}

// Round 7
// 260.112 us; speedup vs baseline: 3.6143x; 3.6143x over previous
//
#include <hip/hip_runtime.h>
#include <hip/hip_bf16.h>

// GRNN tree transform v5: 4 launches.
//  1. k_leaf: leaf emb (=u) + u_small for levels 0..9 + w_h cast (fused)
//  2. k_inner j=11   3. k_inner j=10   (round-4 proven kernels)
//  4. k_fused: levels 9..3 as 512 independent level-3-rooted subtrees in LDS
//     (256 blocks x 2 roots), one hand-rolled 256-block device barrier,
//     then levels 2..0 as 64 level-0-rooted subtrees -> d_out.
// Key fact: children are per-level permutations -> forest of disjoint perfect
// subtrees -> traversal order makes child rows = LDS rows 2i/2i+1.

#define NF 7
#define NH 128
#define NLEAF 262144
#define XSTR 136      // k_inner xs stride (bf16 elems)
#define XSTR3 392     // subtree xs stride: 384 + 8 pad

typedef __bf16 bf16;
typedef __bf16 bf16x8 __attribute__((ext_vector_type(8)));
typedef float floatx16 __attribute__((ext_vector_type(16)));

__device__ __forceinline__ float ftanh(float x){
    float e = __expf(2.0f * x);
    return 1.0f - __fdividef(2.0f, e + 1.0f);
}

// ---------- launch 1: leaf emb + u_small(levels 0..9) + wcast ----------
// grid 2560: blocks [0,2048) leaf tiles (rows 262080+b*128 of contents);
// blocks [2048,2560) u tiles (rows (b-2048)*128, covers 0..65535 >= 65472 needed).
__global__ __launch_bounds__(256) void k_leaf(
    const float* __restrict__ contents, const float* __restrict__ w_u,
    const float* __restrict__ b_u, const float* __restrict__ w_h,
    unsigned int* __restrict__ embA_u32, unsigned int* __restrict__ usm_u32,
    bf16* __restrict__ wb)
{
    __shared__ float csL[128 * 8];
    const int t = threadIdx.x;
    const int b = blockIdx.x;
    if (b < 192) wb[b * 256 + t] = (bf16)w_h[b * 256 + t];

    const int leaf = (b < 2048);
    const size_t srow = leaf ? (262080 + (size_t)b * 128) : ((size_t)(b - 2048) * 128);
    unsigned int* dst = leaf ? embA_u32 : usm_u32;
    const size_t drow = leaf ? ((size_t)b * 128) : ((size_t)(b - 2048) * 128);

    if (t < 224){   // 128*7 floats = 224 float4 (contents reads all in-bounds)
        float4 v = ((const float4*)(contents + srow * NF))[t];
        int e = t * 4;
        float vv[4] = {v.x, v.y, v.z, v.w};
        #pragma unroll
        for (int r = 0; r < 4; ++r){ int ee = e + r; csL[(ee/7)*8 + (ee%7)] = vv[r]; }
    }
    const int cp = t & 63;
    const int quarter = t >> 6;
    float wu0[NF], wu1[NF];
    const float* w0 = w_u + (size_t)(2 * cp) * NF;
    #pragma unroll
    for (int f = 0; f < NF; ++f){ wu0[f] = w0[f]; wu1[f] = w0[NF + f]; }
    const float bu0 = b_u[2 * cp], bu1 = b_u[2 * cp + 1];
    __syncthreads();
    #pragma unroll 4
    for (int i = 0; i < 32; ++i){
        int node = quarter * 32 + i;
        float4 c0 = *(const float4*)&csL[node * 8];
        float4 c1 = *(const float4*)&csL[node * 8 + 4];
        float a0 = bu0, a1 = bu1;
        a0 = fmaf(c0.x, wu0[0], a0); a1 = fmaf(c0.x, wu1[0], a1);
        a0 = fmaf(c0.y, wu0[1], a0); a1 = fmaf(c0.y, wu1[1], a1);
        a0 = fmaf(c0.z, wu0[2], a0); a1 = fmaf(c0.z, wu1[2], a1);
        a0 = fmaf(c0.w, wu0[3], a0); a1 = fmaf(c0.w, wu1[3], a1);
        a0 = fmaf(c1.x, wu0[4], a0); a1 = fmaf(c1.x, wu1[4], a1);
        a0 = fmaf(c1.y, wu0[5], a0); a1 = fmaf(c1.y, wu1[5], a1);
        a0 = fmaf(c1.z, wu0[6], a0); a1 = fmaf(c1.z, wu1[6], a1);
        union { unsigned int u; bf16 h[2]; } pk;
        pk.h[0] = (bf16)ftanh(a0);
        pk.h[1] = (bf16)ftanh(a1);
        dst[(drow + node) * 64 + cp] = pk.u;
    }
}

// ---------- launches 2,3: round-4 k_inner (j=11, j=10) ----------
__global__ __launch_bounds__(256, 4) void k_inner(
    const int2* __restrict__ children, const float* __restrict__ contents,
    const float* __restrict__ w_u, const float* __restrict__ b_u,
    const bf16* __restrict__ wb, const float* __restrict__ b_h,
    const bf16* __restrict__ emb_next, bf16* __restrict__ out_b)
{
    __shared__ bf16 xs[64 * XSTR];
    __shared__ int2 ch_s[64];
    __shared__ float cs[64 * 8];
    const int t = threadIdx.x;
    const int block0 = blockIdx.x * 64;
    if (t < 64) ch_s[t] = children[block0 + t];
    if (t < 112){
        float4 v = ((const float4*)(contents + (size_t)block0 * NF))[t];
        int e = t * 4;
        float vv[4] = {v.x, v.y, v.z, v.w};
        #pragma unroll
        for (int r = 0; r < 4; ++r){ int ee = e + r; cs[(ee/7)*8 + (ee%7)] = vv[r]; }
    }
    const int cp = t & 63;
    const int quarter = t >> 6;
    float wu0[NF], wu1[NF];
    {
        const float* w0 = w_u + (size_t)(2 * cp) * NF;
        #pragma unroll
        for (int f = 0; f < NF; ++f){ wu0[f] = w0[f]; wu1[f] = w0[NF + f]; }
    }
    const float bu0 = b_u[2 * cp], bu1 = b_u[2 * cp + 1];
    const int lane = t & 63;
    const int ct = t >> 6;
    const int m = lane & 31;
    const int q = lane >> 5;
    floatx16 acc0 = {0,0,0,0,0,0,0,0,0,0,0,0,0,0,0,0};
    floatx16 acc1 = {0,0,0,0,0,0,0,0,0,0,0,0,0,0,0,0};
    const bf16* bq = wb + ((size_t)(ct * 32 + m) * 384 + q * 8);
    #pragma unroll 1
    for (int p = 0; p < 3; ++p){
        __syncthreads();
        if (p < 2){
            #pragma unroll
            for (int r = 0; r < 4; ++r){
                int task = r * 256 + t;
                int i = task >> 4, part = task & 15;
                int row = (p == 0) ? ch_s[i].x : ch_s[i].y;
                uint4 v = *(const uint4*)(emb_next + (size_t)row * NH + part * 8);
                *(uint4*)&xs[i * XSTR + part * 8] = v;
            }
        } else {
            #pragma unroll 4
            for (int i = 0; i < 16; ++i){
                int node = quarter * 16 + i;
                float4 c0 = *(const float4*)&cs[node * 8];
                float4 c1 = *(const float4*)&cs[node * 8 + 4];
                float a0 = bu0, a1 = bu1;
                a0 = fmaf(c0.x, wu0[0], a0); a1 = fmaf(c0.x, wu1[0], a1);
                a0 = fmaf(c0.y, wu0[1], a0); a1 = fmaf(c0.y, wu1[1], a1);
                a0 = fmaf(c0.z, wu0[2], a0); a1 = fmaf(c0.z, wu1[2], a1);
                a0 = fmaf(c0.w, wu0[3], a0); a1 = fmaf(c0.w, wu1[3], a1);
                a0 = fmaf(c1.x, wu0[4], a0); a1 = fmaf(c1.x, wu1[4], a1);
                a0 = fmaf(c1.y, wu0[5], a0); a1 = fmaf(c1.y, wu1[5], a1);
                a0 = fmaf(c1.z, wu0[6], a0); a1 = fmaf(c1.z, wu1[6], a1);
                union { unsigned int u; bf16 h[2]; } pk;
                pk.h[0] = (bf16)ftanh(a0);
                pk.h[1] = (bf16)ftanh(a1);
                ((unsigned int*)xs)[node * (XSTR / 2) + cp] = pk.u;
            }
        }
        bf16x8 bfr[8];
        #pragma unroll
        for (int kk = 0; kk < 8; ++kk)
            bfr[kk] = *(const bf16x8*)(bq + p * 128 + kk * 16);
        __syncthreads();
        const bf16* xa = &xs[m * XSTR + q * 8];
        #pragma unroll
        for (int kk = 0; kk < 8; ++kk){
            bf16x8 a0 = *(const bf16x8*)(xa + kk * 16);
            bf16x8 a1 = *(const bf16x8*)(xa + kk * 16 + 32 * XSTR);
            acc0 = __builtin_amdgcn_mfma_f32_32x32x16_bf16(a0, bfr[kk], acc0, 0, 0, 0);
            acc1 = __builtin_amdgcn_mfma_f32_32x32x16_bf16(a1, bfr[kk], acc1, 0, 0, 0);
        }
    }
    const int colg = ct * 32 + m;
    const float bv = b_h[colg];
    #pragma unroll
    for (int nt = 0; nt < 2; ++nt){
        const floatx16* accp = nt ? &acc1 : &acc0;
        #pragma unroll
        for (int r = 0; r < 16; ++r){
            int row  = (r & 3) + 8 * (r >> 2) + 4 * q;
            int node = block0 + nt * 32 + row;
            out_b[(size_t)node * NH + colg] = (bf16)ftanh((*accp)[r] + bv);
        }
    }
}

// ---------- launch 4: subtree kernel ----------
// Bottom-up chain of levels [lbot..ltop] of the subtree rooted at `root`
// (a level-lbot local id). Traversal invariant: level-(l+1) children of
// level-l node i are LDS rows 2i, 2i+1 of the previous step's output.
__device__ __forceinline__ void subtree_run(
    int root, int lbot, int ltop,
    const int2* __restrict__ children, const bf16* __restrict__ u_small,
    const bf16* __restrict__ bottom,   // emb of level ltop+1, by local id
    const bf16* __restrict__ wb, float bv,
    bf16* __restrict__ out_b,          // used when lbot==3 (emb3[root])
    float* __restrict__ out_f,         // used when lbot==0 (d_out[root])
    bf16* xs, bf16* embL, int* ids,
    int t, int ct, int m, int q)
{
    // traversal: level l ids stored at [n-1 .. 2n-2], n = 1<<(l-lbot)
    if (t == 0) ids[0] = root;
    __syncthreads();
    for (int l = lbot; l <= ltop; ++l){
        int n = 1 << (l - lbot), off = n - 1, offc = 2 * n - 1;
        const int2* chl = children + (size_t)64 * ((1u << l) - 1);
        if (t < n){
            int2 c = chl[ids[off + t]];
            ids[offc + 2 * t]     = c.x;
            ids[offc + 2 * t + 1] = c.y;
        }
        __syncthreads();
    }
    const bf16* bq = wb + ((size_t)(ct * 32 + m) * 384 + q * 8);
    #pragma unroll 1
    for (int l = ltop; l >= lbot; --l){
        int n = 1 << (l - lbot), off = n - 1, offc = 2 * n - 1;
        // stage hL/hR (cols 0..255)
        #pragma unroll 1
        for (int r = 0; r < 8; ++r){
            int task = r * 256 + t;
            if (task < n * 32){
                int i = task >> 5, half = (task >> 4) & 1, part = task & 15;
                uint4 v;
                if (l == ltop){
                    int row = ids[offc + 2 * i + half];
                    v = *(const uint4*)(bottom + (size_t)row * NH + part * 8);
                } else {
                    v = *(uint4*)&embL[(2 * i + half) * 136 + part * 8];
                }
                *(uint4*)&xs[i * XSTR3 + half * 128 + part * 8] = v;
            }
        }
        // stage u (cols 256..383) from u_small rows OFFSETS[l]+id
        #pragma unroll 1
        for (int r = 0; r < 4; ++r){
            int task = r * 256 + t;
            if (task < n * 16){
                int i = task >> 4, part = task & 15;
                size_t row = (size_t)64 * ((1u << l) - 1) + ids[off + i];
                *(uint4*)&xs[i * XSTR3 + 256 + part * 8] =
                    *(const uint4*)(u_small + row * NH + part * 8);
            }
        }
        __syncthreads();
        floatx16 acc0 = {0,0,0,0,0,0,0,0,0,0,0,0,0,0,0,0};
        floatx16 acc1 = {0,0,0,0,0,0,0,0,0,0,0,0,0,0,0,0};
        const bf16* xa = &xs[m * XSTR3 + q * 8];
        #pragma unroll
        for (int grp = 0; grp < 3; ++grp){
            bf16x8 bfr[8];
            #pragma unroll
            for (int kk = 0; kk < 8; ++kk)
                bfr[kk] = *(const bf16x8*)(bq + grp * 128 + kk * 16);
            #pragma unroll
            for (int kk = 0; kk < 8; ++kk){
                bf16x8 a0 = *(const bf16x8*)(xa + grp * 128 + kk * 16);
                acc0 = __builtin_amdgcn_mfma_f32_32x32x16_bf16(a0, bfr[kk], acc0, 0, 0, 0);
                if (n > 32){
                    bf16x8 a1 = *(const bf16x8*)(xa + grp * 128 + kk * 16 + 32 * XSTR3);
                    acc1 = __builtin_amdgcn_mfma_f32_32x32x16_bf16(a1, bfr[kk], acc1, 0, 0, 0);
                }
            }
        }
        __syncthreads();   // xs/embL reads done -> safe to overwrite embL
        int ntc = (n + 31) >> 5;
        for (int nt = 0; nt < ntc; ++nt){
            const floatx16* A = nt ? &acc1 : &acc0;
            #pragma unroll
            for (int r = 0; r < 16; ++r){
                int row = nt * 32 + (r & 3) + 8 * (r >> 2) + 4 * q;
                if (row < n){
                    float v = ftanh((*A)[r] + bv);
                    if (l > lbot)       embL[row * 136 + ct * 32 + m] = (bf16)v;
                    else if (out_f)     out_f[(size_t)root * NH + ct * 32 + m] = v;
                    else                out_b[(size_t)root * NH + ct * 32 + m] = (bf16)v;
                }
            }
        }
        __syncthreads();   // embL writes visible before next staging
    }
}

__global__ __launch_bounds__(256, 2) void k_fused(
    const int2* __restrict__ children, const bf16* __restrict__ u_small,
    const bf16* __restrict__ wb, const float* __restrict__ b_h,
    const bf16* __restrict__ emb10, bf16* __restrict__ emb3,
    float* __restrict__ out_f, unsigned int* __restrict__ bar)
{
    __shared__ bf16 xs[64 * XSTR3];    // 50176 B
    __shared__ bf16 embL[64 * 136];    // 17408 B
    __shared__ int ids[256];           // 1024 B  -> ~68.6 KB, 2 blocks/CU
    const int t = threadIdx.x;
    const int ct = t >> 6, lane = t & 63, m = lane & 31, q = lane >> 5;
    const float bv = b_h[ct * 32 + m];

    // phase A: levels 9..3, 512 level-3 roots, 2 per block
    for (int root = blockIdx.x; root < 512; root += 256)
        subtree_run(root, 3, 9, children, u_small, emb10, wb, bv,
                    emb3, nullptr, xs, embL, ids, t, ct, m, q);

    // device barrier over 256 blocks (counter in ws; ws poisoned 0xAA pre-launch)
    __threadfence();
    __syncthreads();
    if (t == 0){
        unsigned int expected = 0xAAAAAAAAu;
        __hip_atomic_compare_exchange_strong(bar, &expected, 0u,
            __ATOMIC_ACQ_REL, __ATOMIC_RELAXED, __HIP_MEMORY_SCOPE_AGENT);
        __hip_atomic_fetch_add(bar, 1u, __ATOMIC_ACQ_REL, __HIP_MEMORY_SCOPE_AGENT);
        while (__hip_atomic_load(bar, __ATOMIC_ACQUIRE, __HIP_MEMORY_SCOPE_AGENT) < 256u)
            __builtin_amdgcn_s_sleep(8);
    }
    __syncthreads();

    // phase B: levels 2..0, 64 level-0 roots -> f32 d_out
    if (blockIdx.x < 64)
        subtree_run(blockIdx.x, 0, 2, children, u_small, emb3, wb, bv,
                    nullptr, out_f, xs, embL, ids, t, ct, m, q);
}

// ---------- launcher ----------
extern "C" void kernel_launch(void* const* d_in, const int* in_sizes, int n_in,
                              void* d_out, int out_size, void* d_ws, size_t ws_size,
                              hipStream_t stream){
    const float* contents = (const float*)d_in[0];
    const int2*  children = (const int2*)d_in[1];
    const float* w_u      = (const float*)d_in[2];
    const float* b_u      = (const float*)d_in[3];
    const float* w_h      = (const float*)d_in[4];
    const float* b_h      = (const float*)d_in[5];
    float* outf = (float*)d_out;

    // ws: embA 67.1MB | embB 33.6MB | wb 96KB | u_small 16.8MB | bar
    bf16* embA    = (bf16*)d_ws;
    bf16* embB    = embA + (size_t)NLEAF * NH;
    bf16* wb      = embB + (size_t)131072 * NH;
    bf16* u_small = wb + (size_t)NH * 384;
    unsigned int* bar = (unsigned int*)(u_small + (size_t)65536 * NH);
    // total ~117.5 MB (ws proven >= 168 MB in round 2)

    hipLaunchKernelGGL(k_leaf, dim3(2560), dim3(256), 0, stream,
                       contents, w_u, b_u, w_h,
                       (unsigned int*)embA, (unsigned int*)u_small, wb);
    // j=11: emb12(embA) -> embB. INNER_OFF[11] = 64*(2^11-1) = 131008
    hipLaunchKernelGGL(k_inner, dim3(2048), dim3(256), 0, stream,
                       children + 131008, contents + (size_t)131008 * NF,
                       w_u, b_u, wb, b_h, embA, embB);
    // j=10: emb11(embB) -> embA. INNER_OFF[10] = 64*(2^10-1) = 65472
    hipLaunchKernelGGL(k_inner, dim3(1024), dim3(256), 0, stream,
                       children + 65472, contents + (size_t)65472 * NF,
                       w_u, b_u, wb, b_h, embB, embA);
    // levels 9..0: emb10 = embA rows [0,65536); emb3 staged in embB rows [0,512)
    hipLaunchKernelGGL(k_fused, dim3(256), dim3(256), 0, stream,
                       children, u_small, wb, b_h, embA, embB, outf, bar);
}